// Round 11
// baseline (805.533 us; speedup 1.0000x reference)
//
#include <hip/hip_runtime.h>
#include <cstdint>
#include <cstddef>

// ---------- types ----------
typedef __attribute__((ext_vector_type(8)))  __bf16 bf16x8;
typedef __attribute__((ext_vector_type(4)))  float  f32x4;
typedef __attribute__((ext_vector_type(2)))  unsigned int u32x2;
typedef __attribute__((ext_vector_type(4)))  unsigned int u32x4;

#define DI __device__ __forceinline__

// ---------- problem constants ----------
constexpr int Cdim = 768;
constexpr int C3   = 2304;
constexpr int NT   = 65;                 // tokens per window (64 + unseen)
constexpr int ROWS = 1024 * NT;          // 66560
constexpr int ROWS_PAD = ROWS + 32;
constexpr int TP   = 96;                 // padded token dim for PV (3 x K32)
constexpr int PS   = 128;                // P LDS row stride in elems
constexpr long long OUT_IMG = 16LL * 4096 * 768;  // 50331648 floats

DI float bf2f(unsigned short u) { unsigned int x = (unsigned int)u << 16; float f; __builtin_memcpy(&f, &x, 4); return f; }
DI unsigned short f2bf(float f) { unsigned int x; __builtin_memcpy(&x, &f, 4); x = x + 0x7fffu + ((x >> 16) & 1u); return (unsigned short)(x >> 16); }

DI void gload_lds16(const unsigned short* g, unsigned short* l) {
  __builtin_amdgcn_global_load_lds((__attribute__((address_space(1))) void*)g,
                                   (__attribute__((address_space(3))) void*)l, 16, 0, 0);
}

// ---------- K0: weights -> bf16, rope table ----------
__global__ void k_prep(const float* __restrict__ qkv_w, const float* __restrict__ proj_w,
                       unsigned short* __restrict__ wqb, unsigned short* __restrict__ wpb,
                       float* __restrict__ rope) {
  const int NW1 = 2304 * 768;
  const int NW2 = 768 * 768;
  int total = NW1 + NW2 + 1024;
  for (int i = blockIdx.x * blockDim.x + threadIdx.x; i < total; i += gridDim.x * blockDim.x) {
    if (i < NW1) wqb[i] = f2bf(qkv_w[i]);
    else if (i < NW1 + NW2) wpb[i - NW1] = f2bf(proj_w[i - NW1]);
    else {
      int e = i - NW1 - NW2;            // e = p*16 + j
      int p = e >> 4, j = e & 15;
      float inv = powf(100.f, -(float)j * (1.f / 16.f));
      float a = (float)p * inv;
      rope[2 * e]     = cosf(a);
      rope[2 * e + 1] = sinf(a);
    }
  }
}

// ---------- K1: window partition + unseen append -> bf16 xw [66560][768] ----------
__global__ void k_xw(const float* __restrict__ x, const float* __restrict__ unseen,
                     unsigned short* __restrict__ xw) {
  int row = blockIdx.x;
  int w = row / NT, t = row - w * NT;
  const float* src;
  if (t == 64) {
    src = unseen + (size_t)(w >> 6) * Cdim;
  } else {
    int wy = (w >> 3) & 7, wx = w & 7;
    int hw = ((wy << 3) + (t >> 3)) * 64 + (wx << 3) + (t & 7);
    src = x + ((size_t)(w >> 6) * 4096 + hw) * Cdim;
  }
  float4 v = ((const float4*)src)[threadIdx.x];
  unsigned int u0 = (unsigned)f2bf(v.x) | ((unsigned)f2bf(v.y) << 16);
  unsigned int u1 = (unsigned)f2bf(v.z) | ((unsigned)f2bf(v.w) << 16);
  ((u32x2*)(xw + (size_t)row * Cdim))[threadIdx.x] = (u32x2){u0, u1};
}

// ---------- GEMM: C[M=66560, N] = A[M,768] @ Bw[N,768]^T + bias ----------
// r10 mainloop (m97 structure, 4-5 blocks/CU). 128x128 tile, BK=64, 4 waves,
// single 32 KB LDS buffer, both-sides XOR-8 swizzle (0 conflicts).
// MODE 0: qkv bf16 + fused RoPE; V-region tiles (n0>=1536) are written
// TRANSPOSED to Vt[w*12+h][d][96] straight from the LDS C-tile (k_vt fused);
// Q/K tiles use the coalesced Cb writeback.
// MODE 1: fp32 window-merge + unseen mean. MW = min waves/EU (occupancy A/B).
template<int MODE, int NTILES, int MW>
__global__ __launch_bounds__(256, MW) void k_gemm(
    const unsigned short* __restrict__ A, const unsigned short* __restrict__ Bw,
    const float* __restrict__ bias, const float* __restrict__ rope,
    unsigned short* __restrict__ Cb, unsigned short* __restrict__ Vt,
    float* __restrict__ outp) {
  constexpr int K = 768;
  __shared__ alignas(16) unsigned short lds[16384];   // 32 KB: As | Bs, epilogue overlay
  unsigned short* As = lds;
  unsigned short* Bs = lds + 8192;

  // bijective XCD swizzle
  constexpr int nwg = 520 * NTILES;
  constexpr int q8 = nwg / 8, r8 = nwg % 8;
  int id = blockIdx.x;
  int xcd = id & 7, lid = id >> 3;
  int wg = (xcd < r8 ? xcd * (q8 + 1) : r8 * (q8 + 1) + (xcd - r8) * q8) + lid;
  int mtile = wg / NTILES, ntile = wg - mtile * NTILES;
  int m0 = mtile * 128, n0 = ntile * 128;

  int tid = threadIdx.x;
  int lane = tid & 63, wid = tid >> 6;
  int lq = lane & 15, lg = lane >> 4;
  int wm = (wid >> 1) * 64;              // wave M offset (0 or 64)
  int wn = (wid & 1) * 64;               // wave N offset (0 or 64)

  f32x4 acc[4][4];
  #pragma unroll
  for (int i = 0; i < 4; ++i)
    #pragma unroll
    for (int j = 0; j < 4; ++j) acc[i][j] = (f32x4){0.f, 0.f, 0.f, 0.f};

  for (int kt = 0; kt < K / 64; ++kt) {
    int k0 = kt * 64;
    #pragma unroll
    for (int c = 0; c < 4; ++c) {
      int chunk = c * 256 + tid;
      int row = chunk >> 3, kc = chunk & 7;
      int skc = kc ^ (row & 7);
      gload_lds16(A + (size_t)(m0 + row) * K + k0 + skc * 8,
                  As + (size_t)(c * 256 + (tid & ~63)) * 8);
    }
    #pragma unroll
    for (int c = 0; c < 4; ++c) {
      int chunk = c * 256 + tid;
      int row = chunk >> 3, kc = chunk & 7;
      int skc = kc ^ (row & 7);
      gload_lds16(Bw + (size_t)(n0 + row) * K + k0 + skc * 8,
                  Bs + (size_t)(c * 256 + (tid & ~63)) * 8);
    }
    asm volatile("s_waitcnt vmcnt(0)" ::: "memory");
    __syncthreads();
    #pragma unroll
    for (int ks = 0; ks < 2; ++ks) {
      bf16x8 af[4], bfr[4];
      #pragma unroll
      for (int mt = 0; mt < 4; ++mt) {
        int row = wm + mt * 16 + lq;
        int ch = ((ks << 2) + lg) ^ (row & 7);
        af[mt] = *(const bf16x8*)(As + row * 64 + ch * 8);
      }
      #pragma unroll
      for (int nt = 0; nt < 4; ++nt) {
        int row = wn + nt * 16 + lq;
        int ch = ((ks << 2) + lg) ^ (row & 7);
        bfr[nt] = *(const bf16x8*)(Bs + row * 64 + ch * 8);
      }
      #pragma unroll
      for (int mt = 0; mt < 4; ++mt)
        #pragma unroll
        for (int nt = 0; nt < 4; ++nt)
          acc[mt][nt] = __builtin_amdgcn_mfma_f32_16x16x32_bf16(af[mt], bfr[nt], acc[mt][nt], 0, 0, 0);
    }
    __syncthreads();
  }

  // ---- coalesced LDS-staged epilogue (overlays the 32 KB LDS) ----
  if (MODE == 0) {
    // C-tile [128][128] bf16 = 32 KB; row stride 256 B; XOR (lrow&7)<<4
    unsigned short* ct = lds;
    #pragma unroll
    for (int mt = 0; mt < 4; ++mt) {
      #pragma unroll
      for (int r = 0; r < 4; ++r) {
        int lrow = wm + mt * 16 + (lg << 2) + r;
        int grow = m0 + lrow;
        int w = grow / NT, t = grow - w * NT;
        int wy = (w >> 3) & 7, wx = w & 7;
        int py = (wy << 3) + (t >> 3), px = (wx << 3) + (t & 7);
        #pragma unroll
        for (int a = 0; a < 2; ++a) {
          int cn0 = wn + a * 32 + lq;          // tile-local col [0,128)
          int col0 = n0 + cn0, col1 = col0 + 16;
          float v0 = acc[mt][2 * a][r] + bias[col0];
          float v1 = acc[mt][2 * a + 1][r] + bias[col1];
          if (col0 < 1536 && t != 64) {        // RoPE on q/k image tokens
            int p = a ? px : py;               // (col0 & 63) >> 5 == a
            const float* rp = rope + ((p << 4) + lq) * 2;
            float cc = rp[0], ss = rp[1];
            float o0 = v0 * cc - v1 * ss;
            float o1 = v1 * cc + v0 * ss;
            v0 = o0; v1 = o1;
          }
          int b0 = (lrow * 256 + cn0 * 2) ^ ((lrow & 7) << 4);
          int b1 = (lrow * 256 + (cn0 + 16) * 2) ^ ((lrow & 7) << 4);
          *(unsigned short*)((char*)ct + b0) = f2bf(v0);
          *(unsigned short*)((char*)ct + b1) = f2bf(v1);
        }
      }
    }
    __syncthreads();
    if (n0 < 1536) {
      // Q/K tile: coalesced writeback to qkv rows
      #pragma unroll
      for (int j = 0; j < 8; ++j) {
        int idx = j * 256 + tid;
        int row = idx >> 4, c = idx & 15;      // 16 16B-chunks per 128-col row
        u32x4 v = *(const u32x4*)((char*)ct + row * 256 + ((c ^ (row & 7)) << 4));
        *(u32x4*)(Cb + (size_t)(m0 + row) * C3 + n0 + c * 8) = v;
      }
    } else {
      // V tile: transposed writeback Vt[w*12+h][d][t], t-octet 16B stores
      int w0 = m0 / NT;
      int nwin = (m0 + 127) / NT - w0 + 1;     // 2..3 windows in tile
      int nitems = nwin * 9 * 128;
      for (int item = tid; item < nitems; item += 256) {
        int c   = item & 127;
        int rst = item >> 7;
        int oc  = rst % 9;                     // t-octet index, t0 = 8*oc
        int w   = w0 + rst / 9;
        int tA = m0 - w * NT; if (tA < 0) tA = 0;
        int tB = m0 + 128 - w * NT; if (tB > NT) tB = NT;
        int t0 = oc * 8;
        int a = t0 > tA ? t0 : tA;
        int b = t0 + 8 < tB ? t0 + 8 : tB;
        if (a >= b) continue;
        int vc = n0 - 1536 + c;
        unsigned short* vrow = Vt + (((size_t)w * 12 + (vc >> 6)) * 64 + (vc & 63)) * TP;
        if (a == t0 && b == t0 + 8) {
          unsigned int u[4];
          #pragma unroll
          for (int k = 0; k < 4; ++k) {
            int ra = w * NT + t0 + 2 * k - m0;
            int rb = ra + 1;
            unsigned short va = *(const unsigned short*)((char*)ct + ((ra * 256 + c * 2) ^ ((ra & 7) << 4)));
            unsigned short vb = *(const unsigned short*)((char*)ct + ((rb * 256 + c * 2) ^ ((rb & 7) << 4)));
            u[k] = (unsigned)va | ((unsigned)vb << 16);
          }
          *(u32x4*)(vrow + t0) = (u32x4){u[0], u[1], u[2], u[3]};
        } else {
          for (int t = a; t < b; ++t) {
            int r = w * NT + t - m0;
            vrow[t] = *(const unsigned short*)((char*)ct + ((r * 256 + c * 2) ^ ((r & 7) << 4)));
          }
        }
      }
    }
  } else {
    // fp32 tile in two 64-row halves: [64][128] f32 = 32 KB each
    float* cf = (float*)lds;
    #pragma unroll
    for (int half = 0; half < 2; ++half) {
      if ((wm >> 6) == half) {
        #pragma unroll
        for (int mt = 0; mt < 4; ++mt) {
          #pragma unroll
          for (int r = 0; r < 4; ++r) {
            int lrow = mt * 16 + (lg << 2) + r;  // 0..63
            int grow = m0 + half * 64 + lrow;
            int w = grow / NT, t = grow - w * NT;
            #pragma unroll
            for (int a = 0; a < 2; ++a) {
              int cn0 = wn + a * 32 + lq;
              int col0 = n0 + cn0, col1 = col0 + 16;
              float v0 = acc[mt][2 * a][r] + bias[col0];
              float v1 = acc[mt][2 * a + 1][r] + bias[col1];
              if (t == 64) {
                float* ub = outp + OUT_IMG + (size_t)(w >> 6) * Cdim;
                atomicAdd(ub + col0, v0 * (1.f / 64.f));
                atomicAdd(ub + col1, v1 * (1.f / 64.f));
              } else {
                int b0 = (lrow * 512 + cn0 * 4) ^ ((lrow & 7) << 4);
                int b1 = (lrow * 512 + (cn0 + 16) * 4) ^ ((lrow & 7) << 4);
                *(float*)((char*)cf + b0) = v0;
                *(float*)((char*)cf + b1) = v1;
              }
            }
          }
        }
      }
      __syncthreads();
      #pragma unroll
      for (int j = 0; j < 8; ++j) {
        int idx = j * 256 + tid;
        int row = idx >> 5, c = idx & 31;      // 32 16B-chunks per 128-col row
        int grow = m0 + half * 64 + row;
        int w = grow / NT, t = grow - w * NT;
        if (t != 64) {
          int wy = (w >> 3) & 7, wx = w & 7;
          int py = (wy << 3) + (t >> 3), px = (wx << 3) + (t & 7);
          u32x4 v = *(const u32x4*)((char*)cf + row * 512 + ((c ^ (row & 7)) << 4));
          *(u32x4*)(outp + ((size_t)(w >> 6) * 4096 + py * 64 + px) * Cdim + n0 + c * 4) = v;
        }
      }
      __syncthreads();
    }
  }
}

// ---------- K4: attention, 1 wave per (window, head); 4 KB LDS (16-row P) ----------
__global__ __launch_bounds__(64) void k_attn(const unsigned short* __restrict__ qkv,
                                             const unsigned short* __restrict__ Vt,
                                             unsigned short* __restrict__ att) {
  __shared__ alignas(16) unsigned short P[16 * PS];   // 4 KB: rows indexed by lq
  int h = blockIdx.x, w = blockIdx.y;
  int lane = threadIdx.x;
  int lq = lane & 15, lg = lane >> 4;

  const unsigned short* qb = qkv + (size_t)w * NT * C3 + h * 64;
  const unsigned short* kb = qb + 768;

  bf16x8 kf[5][2];
  #pragma unroll
  for (int kt = 0; kt < 5; ++kt)
    #pragma unroll
    for (int ks = 0; ks < 2; ++ks)
      kf[kt][ks] = *(const bf16x8*)(kb + (size_t)(kt * 16 + lq) * C3 + ks * 32 + lg * 8);

  const unsigned short* vb = Vt + (size_t)(w * 12 + h) * 64 * TP;
  bf16x8 vf[3][4];
  #pragma unroll
  for (int ks = 0; ks < 3; ++ks)
    #pragma unroll
    for (int dt = 0; dt < 4; ++dt)
      vf[ks][dt] = *(const bf16x8*)(vb + (size_t)(dt * 16 + lq) * TP + ks * 32 + lg * 8);

  // zero the t in [80,96) region of each P row (never written by pv stores)
  for (int i = lane; i < 16 * 8; i += 64) {
    int row = i >> 3, j = i & 7;
    int byteo = (row * (PS * 2) + 160 + j * 4) ^ ((row & 7) << 4);
    *(unsigned int*)((char*)P + byteo) = 0u;
  }

  #pragma unroll 1
  for (int qt = 0; qt < 5; ++qt) {
    bf16x8 qf[2];
    #pragma unroll
    for (int ks = 0; ks < 2; ++ks)
      qf[ks] = *(const bf16x8*)(qb + (size_t)(qt * 16 + lq) * C3 + ks * 32 + lg * 8);

    f32x4 sa[5];
    #pragma unroll
    for (int kt = 0; kt < 5; ++kt) {
      sa[kt] = (f32x4){0.f, 0.f, 0.f, 0.f};
      #pragma unroll
      for (int ks = 0; ks < 2; ++ks)
        sa[kt] = __builtin_amdgcn_mfma_f32_16x16x32_bf16(kf[kt][ks], qf[ks], sa[kt], 0, 0, 0);
    }
    float pv[5][4];
    float m = -1e30f;
    #pragma unroll
    for (int kt = 0; kt < 5; ++kt)
      #pragma unroll
      for (int r = 0; r < 4; ++r) {
        int tok = kt * 16 + lg * 4 + r;
        float s = sa[kt][r] * 0.125f;
        bool ok = tok < 65;
        pv[kt][r] = ok ? s : -1e30f;
        m = (ok && s > m) ? s : m;
      }
    m = fmaxf(m, __shfl_xor(m, 16));
    m = fmaxf(m, __shfl_xor(m, 32));
    float sum = 0.f;
    #pragma unroll
    for (int kt = 0; kt < 5; ++kt)
      #pragma unroll
      for (int r = 0; r < 4; ++r) {
        float e = (pv[kt][r] > -1e29f) ? exp2f((pv[kt][r] - m) * 1.44269504f) : 0.f;
        pv[kt][r] = e;
        sum += e;
      }
    sum += __shfl_xor(sum, 16);
    sum += __shfl_xor(sum, 32);
    float rinv = 1.f / sum;

    int q = qt * 16 + lq;
    #pragma unroll
    for (int kt = 0; kt < 5; ++kt) {
      unsigned int u0 = (unsigned)f2bf(pv[kt][0] * rinv) | ((unsigned)f2bf(pv[kt][1] * rinv) << 16);
      unsigned int u1 = (unsigned)f2bf(pv[kt][2] * rinv) | ((unsigned)f2bf(pv[kt][3] * rinv) << 16);
      int byteo = (lq * (PS * 2) + kt * 32 + lg * 8) ^ ((lq & 7) << 4);
      *(u32x2*)((char*)P + byteo) = (u32x2){u0, u1};
    }
    asm volatile("s_waitcnt lgkmcnt(0)" ::: "memory");

    bf16x8 bp[3];
    #pragma unroll
    for (int ks = 0; ks < 3; ++ks) {
      int byteo = (lq * (PS * 2) + ks * 64 + lg * 16) ^ ((lq & 7) << 4);
      bp[ks] = *(const bf16x8*)((char*)P + byteo);
    }
    #pragma unroll
    for (int dt = 0; dt < 4; ++dt) {
      f32x4 o = (f32x4){0.f, 0.f, 0.f, 0.f};
      #pragma unroll
      for (int ks = 0; ks < 3; ++ks)
        o = __builtin_amdgcn_mfma_f32_16x16x32_bf16(vf[ks][dt], bp[ks], o, 0, 0, 0);
      if (q < 65) {
        unsigned int u0 = (unsigned)f2bf(o[0]) | ((unsigned)f2bf(o[1]) << 16);
        unsigned int u1 = (unsigned)f2bf(o[2]) | ((unsigned)f2bf(o[3]) << 16);
        *(u32x2*)(att + (size_t)(w * NT + q) * Cdim + h * 64 + dt * 16 + lg * 4) = (u32x2){u0, u1};
      }
    }
  }
}

// ---------- host ----------
extern "C" void kernel_launch(void* const* d_in, const int* in_sizes, int n_in,
                              void* d_out, int out_size, void* d_ws, size_t ws_size,
                              hipStream_t stream) {
  const float* x_img  = (const float*)d_in[0];
  const float* unseen = (const float*)d_in[2];
  const float* qkv_w  = (const float*)d_in[3];
  const float* qkv_b  = (const float*)d_in[4];
  const float* proj_w = (const float*)d_in[5];
  const float* proj_b = (const float*)d_in[6];

  char* ws = (char*)d_ws;
  size_t off = 0;
  auto alloc = [&](size_t bytes) { void* p = ws + off; off = (off + bytes + 255) & ~(size_t)255; return p; };
  unsigned short* xw  = (unsigned short*)alloc((size_t)ROWS * Cdim * 2);
  unsigned short* qkv = (unsigned short*)alloc((size_t)ROWS_PAD * C3 * 2);
  unsigned short* Vt  = (unsigned short*)alloc((size_t)12288 * 64 * TP * 2);
  unsigned short* wqb = (unsigned short*)alloc((size_t)C3 * Cdim * 2);
  unsigned short* wpb = (unsigned short*)alloc((size_t)Cdim * Cdim * 2);
  float* rope = (float*)alloc(64 * 16 * 2 * sizeof(float));

  hipMemsetAsync((float*)d_out + OUT_IMG, 0, 16 * Cdim * sizeof(float), stream);

  k_prep<<<512, 256, 0, stream>>>(qkv_w, proj_w, wqb, wpb, rope);
  k_xw<<<ROWS, 192, 0, stream>>>(x_img, unseen, xw);
  k_gemm<0, 18, 4><<<520 * 18, 256, 0, stream>>>(xw, wqb, qkv_b, rope, qkv, Vt, nullptr);
  k_attn<<<dim3(12, 1024), 64, 0, stream>>>(qkv, Vt, xw);
  k_gemm<1, 6, 5><<<520 * 6, 256, 0, stream>>>(xw, wpb, proj_b, nullptr, nullptr, nullptr, (float*)d_out);
}

// Round 12
// 657.217 us; speedup vs baseline: 1.2257x; 1.2257x over previous
//
#include <hip/hip_runtime.h>
#include <cstdint>
#include <cstddef>

// ---------- types ----------
typedef __attribute__((ext_vector_type(8)))  __bf16 bf16x8;
typedef __attribute__((ext_vector_type(4)))  float  f32x4;
typedef __attribute__((ext_vector_type(2)))  unsigned int u32x2;
typedef __attribute__((ext_vector_type(4)))  unsigned int u32x4;

#define DI __device__ __forceinline__

// ---------- problem constants ----------
constexpr int Cdim = 768;
constexpr int C3   = 2304;
constexpr int NT   = 65;                 // tokens per window (64 + unseen)
constexpr int ROWS = 1024 * NT;          // 66560
constexpr int ROWS_PAD = ROWS + 32;
constexpr int TP   = 96;                 // padded token dim for PV (3 x K32)
constexpr int PS   = 128;                // P LDS row stride in elems
constexpr long long OUT_IMG = 16LL * 4096 * 768;  // 50331648 floats

DI float bf2f(unsigned short u) { unsigned int x = (unsigned int)u << 16; float f; __builtin_memcpy(&f, &x, 4); return f; }
DI unsigned short f2bf(float f) { unsigned int x; __builtin_memcpy(&x, &f, 4); x = x + 0x7fffu + ((x >> 16) & 1u); return (unsigned short)(x >> 16); }

DI void gload_lds16(const unsigned short* g, unsigned short* l) {
  __builtin_amdgcn_global_load_lds((__attribute__((address_space(1))) void*)g,
                                   (__attribute__((address_space(3))) void*)l, 16, 0, 0);
}

// ---------- K0: weights -> bf16, rope table ----------
__global__ void k_prep(const float* __restrict__ qkv_w, const float* __restrict__ proj_w,
                       unsigned short* __restrict__ wqb, unsigned short* __restrict__ wpb,
                       float* __restrict__ rope) {
  const int NW1 = 2304 * 768;
  const int NW2 = 768 * 768;
  int total = NW1 + NW2 + 1024;
  for (int i = blockIdx.x * blockDim.x + threadIdx.x; i < total; i += gridDim.x * blockDim.x) {
    if (i < NW1) wqb[i] = f2bf(qkv_w[i]);
    else if (i < NW1 + NW2) wpb[i - NW1] = f2bf(proj_w[i - NW1]);
    else {
      int e = i - NW1 - NW2;            // e = p*16 + j
      int p = e >> 4, j = e & 15;
      float inv = powf(100.f, -(float)j * (1.f / 16.f));
      float a = (float)p * inv;
      rope[2 * e]     = cosf(a);
      rope[2 * e + 1] = sinf(a);
    }
  }
}

// ---------- K1: window partition + unseen append -> bf16 xw [66560][768] ----------
__global__ void k_xw(const float* __restrict__ x, const float* __restrict__ unseen,
                     unsigned short* __restrict__ xw) {
  int row = blockIdx.x;
  int w = row / NT, t = row - w * NT;
  const float* src;
  if (t == 64) {
    src = unseen + (size_t)(w >> 6) * Cdim;
  } else {
    int wy = (w >> 3) & 7, wx = w & 7;
    int hw = ((wy << 3) + (t >> 3)) * 64 + (wx << 3) + (t & 7);
    src = x + ((size_t)(w >> 6) * 4096 + hw) * Cdim;
  }
  float4 v = ((const float4*)src)[threadIdx.x];
  unsigned int u0 = (unsigned)f2bf(v.x) | ((unsigned)f2bf(v.y) << 16);
  unsigned int u1 = (unsigned)f2bf(v.z) | ((unsigned)f2bf(v.w) << 16);
  ((u32x2*)(xw + (size_t)row * Cdim))[threadIdx.x] = (u32x2){u0, u1};
}

// ---------- GEMM: C[M=66560, N] = A[M,768] @ Bw[N,768]^T + bias ----------
// r10 configuration (proven 317 us QKV): m97 mainloop, 128x128 tile, BK=64,
// 4 waves 2x2 (64x64 each), single 32 KB LDS buffer, 4 blocks/CU
// (launch_bounds 256,4), both-sides XOR-8 swizzle (0 conflicts), coalesced
// LDS-staged epilogue. MODE 0: qkv bf16 + fused RoPE. MODE 1: fp32
// window-merge + unseen mean.
template<int MODE, int NTILES>
__global__ __launch_bounds__(256, 4) void k_gemm(
    const unsigned short* __restrict__ A, const unsigned short* __restrict__ Bw,
    const float* __restrict__ bias, const float* __restrict__ rope,
    unsigned short* __restrict__ Cb, float* __restrict__ outp) {
  constexpr int K = 768;
  __shared__ alignas(16) unsigned short As[128 * 64];   // 16 KB
  __shared__ alignas(16) unsigned short Bs[128 * 64];   // 16 KB

  // bijective XCD swizzle
  constexpr int nwg = 520 * NTILES;
  constexpr int q8 = nwg / 8, r8 = nwg % 8;
  int id = blockIdx.x;
  int xcd = id & 7, lid = id >> 3;
  int wg = (xcd < r8 ? xcd * (q8 + 1) : r8 * (q8 + 1) + (xcd - r8) * q8) + lid;
  int mtile = wg / NTILES, ntile = wg - mtile * NTILES;
  int m0 = mtile * 128, n0 = ntile * 128;

  int tid = threadIdx.x;
  int lane = tid & 63, wid = tid >> 6;
  int lq = lane & 15, lg = lane >> 4;
  int wm = (wid >> 1) * 64;              // wave M offset (0 or 64)
  int wn = (wid & 1) * 64;               // wave N offset (0 or 64)

  f32x4 acc[4][4];
  #pragma unroll
  for (int i = 0; i < 4; ++i)
    #pragma unroll
    for (int j = 0; j < 4; ++j) acc[i][j] = (f32x4){0.f, 0.f, 0.f, 0.f};

  for (int kt = 0; kt < K / 64; ++kt) {
    int k0 = kt * 64;
    #pragma unroll
    for (int c = 0; c < 4; ++c) {
      int chunk = c * 256 + tid;
      int row = chunk >> 3, kc = chunk & 7;
      int skc = kc ^ (row & 7);
      gload_lds16(A + (size_t)(m0 + row) * K + k0 + skc * 8,
                  As + (size_t)(c * 256 + (tid & ~63)) * 8);
    }
    #pragma unroll
    for (int c = 0; c < 4; ++c) {
      int chunk = c * 256 + tid;
      int row = chunk >> 3, kc = chunk & 7;
      int skc = kc ^ (row & 7);
      gload_lds16(Bw + (size_t)(n0 + row) * K + k0 + skc * 8,
                  Bs + (size_t)(c * 256 + (tid & ~63)) * 8);
    }
    asm volatile("s_waitcnt vmcnt(0)" ::: "memory");
    __syncthreads();
    #pragma unroll
    for (int ks = 0; ks < 2; ++ks) {
      bf16x8 af[4], bfr[4];
      #pragma unroll
      for (int mt = 0; mt < 4; ++mt) {
        int row = wm + mt * 16 + lq;
        int ch = ((ks << 2) + lg) ^ (row & 7);
        af[mt] = *(const bf16x8*)(As + row * 64 + ch * 8);
      }
      #pragma unroll
      for (int nt = 0; nt < 4; ++nt) {
        int row = wn + nt * 16 + lq;
        int ch = ((ks << 2) + lg) ^ (row & 7);
        bfr[nt] = *(const bf16x8*)(Bs + row * 64 + ch * 8);
      }
      #pragma unroll
      for (int mt = 0; mt < 4; ++mt)
        #pragma unroll
        for (int nt = 0; nt < 4; ++nt)
          acc[mt][nt] = __builtin_amdgcn_mfma_f32_16x16x32_bf16(af[mt], bfr[nt], acc[mt][nt], 0, 0, 0);
    }
    __syncthreads();
  }

  // ---- coalesced LDS-staged epilogue (overlays As/Bs: 32 KB) ----
  if (MODE == 0) {
    // C-tile [128][128] bf16 = 32 KB; row stride 256 B; XOR (lrow&7)<<4
    unsigned short* ct = As;
    #pragma unroll
    for (int mt = 0; mt < 4; ++mt) {
      #pragma unroll
      for (int r = 0; r < 4; ++r) {
        int lrow = wm + mt * 16 + (lg << 2) + r;
        int grow = m0 + lrow;
        int w = grow / NT, t = grow - w * NT;
        int wy = (w >> 3) & 7, wx = w & 7;
        int py = (wy << 3) + (t >> 3), px = (wx << 3) + (t & 7);
        #pragma unroll
        for (int a = 0; a < 2; ++a) {
          int cn0 = wn + a * 32 + lq;          // tile-local col [0,128)
          int col0 = n0 + cn0, col1 = col0 + 16;
          float v0 = acc[mt][2 * a][r] + bias[col0];
          float v1 = acc[mt][2 * a + 1][r] + bias[col1];
          if (col0 < 1536 && t != 64) {        // RoPE on q/k image tokens
            int p = a ? px : py;               // (col0 & 63) >> 5 == a
            const float* rp = rope + ((p << 4) + lq) * 2;
            float cc = rp[0], ss = rp[1];
            float o0 = v0 * cc - v1 * ss;
            float o1 = v1 * cc + v0 * ss;
            v0 = o0; v1 = o1;
          }
          int b0 = (lrow * 256 + cn0 * 2) ^ ((lrow & 7) << 4);
          int b1 = (lrow * 256 + (cn0 + 16) * 2) ^ ((lrow & 7) << 4);
          *(unsigned short*)((char*)ct + b0) = f2bf(v0);
          *(unsigned short*)((char*)ct + b1) = f2bf(v1);
        }
      }
    }
    __syncthreads();
    #pragma unroll
    for (int j = 0; j < 8; ++j) {
      int idx = j * 256 + tid;
      int row = idx >> 4, c = idx & 15;        // 16 16B-chunks per 128-col row
      u32x4 v = *(const u32x4*)((char*)ct + row * 256 + ((c ^ (row & 7)) << 4));
      *(u32x4*)(Cb + (size_t)(m0 + row) * C3 + n0 + c * 8) = v;
    }
  } else {
    // fp32 tile in two 64-row halves: [64][128] f32 = 32 KB each
    float* cf = (float*)As;
    #pragma unroll
    for (int half = 0; half < 2; ++half) {
      if ((wm >> 6) == half) {
        #pragma unroll
        for (int mt = 0; mt < 4; ++mt) {
          #pragma unroll
          for (int r = 0; r < 4; ++r) {
            int lrow = mt * 16 + (lg << 2) + r;  // 0..63
            int grow = m0 + half * 64 + lrow;
            int w = grow / NT, t = grow - w * NT;
            #pragma unroll
            for (int a = 0; a < 2; ++a) {
              int cn0 = wn + a * 32 + lq;
              int col0 = n0 + cn0, col1 = col0 + 16;
              float v0 = acc[mt][2 * a][r] + bias[col0];
              float v1 = acc[mt][2 * a + 1][r] + bias[col1];
              if (t == 64) {
                float* ub = outp + OUT_IMG + (size_t)(w >> 6) * Cdim;
                atomicAdd(ub + col0, v0 * (1.f / 64.f));
                atomicAdd(ub + col1, v1 * (1.f / 64.f));
              } else {
                int b0 = (lrow * 512 + cn0 * 4) ^ ((lrow & 7) << 4);
                int b1 = (lrow * 512 + (cn0 + 16) * 4) ^ ((lrow & 7) << 4);
                *(float*)((char*)cf + b0) = v0;
                *(float*)((char*)cf + b1) = v1;
              }
            }
          }
        }
      }
      __syncthreads();
      #pragma unroll
      for (int j = 0; j < 8; ++j) {
        int idx = j * 256 + tid;
        int row = idx >> 5, c = idx & 31;      // 32 16B-chunks per 128-col row
        int grow = m0 + half * 64 + row;
        int w = grow / NT, t = grow - w * NT;
        if (t != 64) {
          int wy = (w >> 3) & 7, wx = w & 7;
          int py = (wy << 3) + (t >> 3), px = (wx << 3) + (t & 7);
          u32x4 v = *(const u32x4*)((char*)cf + row * 512 + ((c ^ (row & 7)) << 4));
          *(u32x4*)(outp + ((size_t)(w >> 6) * 4096 + py * 64 + px) * Cdim + n0 + c * 4) = v;
        }
      }
      __syncthreads();
    }
  }
}

// ---------- K3: V transpose per (window, head); vectorized 16B output ----------
__global__ void k_vt(const unsigned short* __restrict__ qkv, unsigned short* __restrict__ Vt) {
  int bh = blockIdx.x;
  int w = bh / 12, h = bh - w * 12;
  __shared__ float sv[65][65];
  const unsigned short* base = qkv + (size_t)w * NT * C3 + 1536 + h * 64;
  for (int i = threadIdx.x; i < 65 * 64; i += 256) {
    int t = i >> 6, d = i & 63;
    sv[t][d] = bf2f(base[(size_t)t * C3 + d]);
  }
  __syncthreads();
  unsigned short* out = Vt + (size_t)bh * 64 * TP;
  for (int i = threadIdx.x; i < 64 * (TP / 8); i += 256) {
    int d = i / (TP / 8), tc = i - d * (TP / 8);
    int t0 = tc * 8;
    unsigned int u[4];
    #pragma unroll
    for (int k = 0; k < 4; ++k) {
      int ta = t0 + 2 * k, tb = ta + 1;
      unsigned short sa = (ta < 65) ? f2bf(sv[ta][d]) : (unsigned short)0;
      unsigned short sb = (tb < 65) ? f2bf(sv[tb][d]) : (unsigned short)0;
      u[k] = (unsigned)sa | ((unsigned)sb << 16);
    }
    *(u32x4*)(out + d * TP + t0) = (u32x4){u[0], u[1], u[2], u[3]};
  }
}

// ---------- K4: attention, 1 wave per (window, head) ----------
// SINGLE CHANGE vs r10: P shrunk 80 rows -> 16 lq-indexed rows (20.5 KB ->
// 4 KB). Addresses identical mod row base (q&7 == lq&7); lifts LDS
// occupancy cap 7 -> ~40 blocks/CU (VGPR becomes the limiter).
__global__ __launch_bounds__(64) void k_attn(const unsigned short* __restrict__ qkv,
                                             const unsigned short* __restrict__ Vt,
                                             unsigned short* __restrict__ att) {
  __shared__ alignas(16) unsigned short P[16 * PS];   // 4 KB
  int h = blockIdx.x, w = blockIdx.y;
  int lane = threadIdx.x;
  int lq = lane & 15, lg = lane >> 4;

  const unsigned short* qb = qkv + (size_t)w * NT * C3 + h * 64;
  const unsigned short* kb = qb + 768;

  bf16x8 kf[5][2];
  #pragma unroll
  for (int kt = 0; kt < 5; ++kt)
    #pragma unroll
    for (int ks = 0; ks < 2; ++ks)
      kf[kt][ks] = *(const bf16x8*)(kb + (size_t)(kt * 16 + lq) * C3 + ks * 32 + lg * 8);

  const unsigned short* vb = Vt + (size_t)(w * 12 + h) * 64 * TP;
  bf16x8 vf[3][4];
  #pragma unroll
  for (int ks = 0; ks < 3; ++ks)
    #pragma unroll
    for (int dt = 0; dt < 4; ++dt)
      vf[ks][dt] = *(const bf16x8*)(vb + (size_t)(dt * 16 + lq) * TP + ks * 32 + lg * 8);

  // zero the t in [80,96) region of each P row (never written by pv stores)
  for (int i = lane; i < 16 * 8; i += 64) {
    int row = i >> 3, j = i & 7;
    int byteo = (row * (PS * 2) + 160 + j * 4) ^ ((row & 7) << 4);
    *(unsigned int*)((char*)P + byteo) = 0u;
  }

  #pragma unroll 1
  for (int qt = 0; qt < 5; ++qt) {
    bf16x8 qf[2];
    #pragma unroll
    for (int ks = 0; ks < 2; ++ks)
      qf[ks] = *(const bf16x8*)(qb + (size_t)(qt * 16 + lq) * C3 + ks * 32 + lg * 8);

    f32x4 sa[5];
    #pragma unroll
    for (int kt = 0; kt < 5; ++kt) {
      sa[kt] = (f32x4){0.f, 0.f, 0.f, 0.f};
      #pragma unroll
      for (int ks = 0; ks < 2; ++ks)
        sa[kt] = __builtin_amdgcn_mfma_f32_16x16x32_bf16(kf[kt][ks], qf[ks], sa[kt], 0, 0, 0);
    }
    float pv[5][4];
    float m = -1e30f;
    #pragma unroll
    for (int kt = 0; kt < 5; ++kt)
      #pragma unroll
      for (int r = 0; r < 4; ++r) {
        int tok = kt * 16 + lg * 4 + r;
        float s = sa[kt][r] * 0.125f;
        bool ok = tok < 65;
        pv[kt][r] = ok ? s : -1e30f;
        m = (ok && s > m) ? s : m;
      }
    m = fmaxf(m, __shfl_xor(m, 16));
    m = fmaxf(m, __shfl_xor(m, 32));
    float sum = 0.f;
    #pragma unroll
    for (int kt = 0; kt < 5; ++kt)
      #pragma unroll
      for (int r = 0; r < 4; ++r) {
        float e = (pv[kt][r] > -1e29f) ? exp2f((pv[kt][r] - m) * 1.44269504f) : 0.f;
        pv[kt][r] = e;
        sum += e;
      }
    sum += __shfl_xor(sum, 16);
    sum += __shfl_xor(sum, 32);
    float rinv = 1.f / sum;

    int q = qt * 16 + lq;
    #pragma unroll
    for (int kt = 0; kt < 5; ++kt) {
      unsigned int u0 = (unsigned)f2bf(pv[kt][0] * rinv) | ((unsigned)f2bf(pv[kt][1] * rinv) << 16);
      unsigned int u1 = (unsigned)f2bf(pv[kt][2] * rinv) | ((unsigned)f2bf(pv[kt][3] * rinv) << 16);
      int byteo = (lq * (PS * 2) + kt * 32 + lg * 8) ^ ((lq & 7) << 4);
      *(u32x2*)((char*)P + byteo) = (u32x2){u0, u1};
    }
    asm volatile("s_waitcnt lgkmcnt(0)" ::: "memory");

    bf16x8 bp[3];
    #pragma unroll
    for (int ks = 0; ks < 3; ++ks) {
      int byteo = (lq * (PS * 2) + ks * 64 + lg * 16) ^ ((lq & 7) << 4);
      bp[ks] = *(const bf16x8*)((char*)P + byteo);
    }
    #pragma unroll
    for (int dt = 0; dt < 4; ++dt) {
      f32x4 o = (f32x4){0.f, 0.f, 0.f, 0.f};
      #pragma unroll
      for (int ks = 0; ks < 3; ++ks)
        o = __builtin_amdgcn_mfma_f32_16x16x32_bf16(vf[ks][dt], bp[ks], o, 0, 0, 0);
      if (q < 65) {
        unsigned int u0 = (unsigned)f2bf(o[0]) | ((unsigned)f2bf(o[1]) << 16);
        unsigned int u1 = (unsigned)f2bf(o[2]) | ((unsigned)f2bf(o[3]) << 16);
        *(u32x2*)(att + (size_t)(w * NT + q) * Cdim + h * 64 + dt * 16 + lg * 4) = (u32x2){u0, u1};
      }
    }
  }
}

// ---------- host ----------
extern "C" void kernel_launch(void* const* d_in, const int* in_sizes, int n_in,
                              void* d_out, int out_size, void* d_ws, size_t ws_size,
                              hipStream_t stream) {
  const float* x_img  = (const float*)d_in[0];
  const float* unseen = (const float*)d_in[2];
  const float* qkv_w  = (const float*)d_in[3];
  const float* qkv_b  = (const float*)d_in[4];
  const float* proj_w = (const float*)d_in[5];
  const float* proj_b = (const float*)d_in[6];

  char* ws = (char*)d_ws;
  size_t off = 0;
  auto alloc = [&](size_t bytes) { void* p = ws + off; off = (off + bytes + 255) & ~(size_t)255; return p; };
  unsigned short* xw  = (unsigned short*)alloc((size_t)ROWS * Cdim * 2);
  unsigned short* qkv = (unsigned short*)alloc((size_t)ROWS_PAD * C3 * 2);
  unsigned short* Vt  = (unsigned short*)alloc((size_t)12288 * 64 * TP * 2);
  unsigned short* wqb = (unsigned short*)alloc((size_t)C3 * Cdim * 2);
  unsigned short* wpb = (unsigned short*)alloc((size_t)Cdim * Cdim * 2);
  float* rope = (float*)alloc(64 * 16 * 2 * sizeof(float));

  hipMemsetAsync((float*)d_out + OUT_IMG, 0, 16 * Cdim * sizeof(float), stream);

  k_prep<<<512, 256, 0, stream>>>(qkv_w, proj_w, wqb, wpb, rope);
  k_xw<<<ROWS, 192, 0, stream>>>(x_img, unseen, xw);
  k_gemm<0, 18><<<520 * 18, 256, 0, stream>>>(xw, wqb, qkv_b, rope, qkv, nullptr);
  k_vt<<<12288, 256, 0, stream>>>(qkv, Vt);
  k_attn<<<dim3(12, 1024), 64, 0, stream>>>(qkv, Vt, xw);
  k_gemm<1, 6><<<520 * 6, 256, 0, stream>>>(xw, wpb, proj_b, nullptr, nullptr, (float*)d_out);
}

// Round 13
// 594.692 us; speedup vs baseline: 1.3545x; 1.1051x over previous
//
#include <hip/hip_runtime.h>
#include <cstdint>
#include <cstddef>

// ---------- types ----------
typedef __attribute__((ext_vector_type(8)))  __bf16 bf16x8;
typedef __attribute__((ext_vector_type(4)))  float  f32x4;
typedef __attribute__((ext_vector_type(2)))  unsigned int u32x2;
typedef __attribute__((ext_vector_type(4)))  unsigned int u32x4;

#define DI __device__ __forceinline__

// ---------- problem constants ----------
constexpr int Cdim = 768;
constexpr int C3   = 2304;
constexpr int NT   = 65;                 // tokens per window (64 + unseen)
constexpr int ROWS = 1024 * NT;          // 66560
constexpr int ROWS_PAD = ROWS + 32;
constexpr int PS   = 128;                // P LDS row stride in elems
constexpr long long OUT_IMG = 16LL * 4096 * 768;  // 50331648 floats

DI float bf2f(unsigned short u) { unsigned int x = (unsigned int)u << 16; float f; __builtin_memcpy(&f, &x, 4); return f; }
DI unsigned short f2bf(float f) { unsigned int x; __builtin_memcpy(&x, &f, 4); x = x + 0x7fffu + ((x >> 16) & 1u); return (unsigned short)(x >> 16); }

DI void gload_lds16(const unsigned short* g, unsigned short* l) {
  __builtin_amdgcn_global_load_lds((__attribute__((address_space(1))) void*)g,
                                   (__attribute__((address_space(3))) void*)l, 16, 0, 0);
}

// ---------- K0: weights -> bf16, rope table ----------
__global__ void k_prep(const float* __restrict__ qkv_w, const float* __restrict__ proj_w,
                       unsigned short* __restrict__ wqb, unsigned short* __restrict__ wpb,
                       float* __restrict__ rope) {
  const int NW1 = 2304 * 768;
  const int NW2 = 768 * 768;
  int total = NW1 + NW2 + 1024;
  for (int i = blockIdx.x * blockDim.x + threadIdx.x; i < total; i += gridDim.x * blockDim.x) {
    if (i < NW1) wqb[i] = f2bf(qkv_w[i]);
    else if (i < NW1 + NW2) wpb[i - NW1] = f2bf(proj_w[i - NW1]);
    else {
      int e = i - NW1 - NW2;            // e = p*16 + j
      int p = e >> 4, j = e & 15;
      float inv = powf(100.f, -(float)j * (1.f / 16.f));
      float a = (float)p * inv;
      rope[2 * e]     = cosf(a);
      rope[2 * e + 1] = sinf(a);
    }
  }
}

// ---------- K1: window partition + unseen append -> bf16 xw [66560][768] ----------
__global__ void k_xw(const float* __restrict__ x, const float* __restrict__ unseen,
                     unsigned short* __restrict__ xw) {
  int row = blockIdx.x;
  int w = row / NT, t = row - w * NT;
  const float* src;
  if (t == 64) {
    src = unseen + (size_t)(w >> 6) * Cdim;
  } else {
    int wy = (w >> 3) & 7, wx = w & 7;
    int hw = ((wy << 3) + (t >> 3)) * 64 + (wx << 3) + (t & 7);
    src = x + ((size_t)(w >> 6) * 4096 + hw) * Cdim;
  }
  float4 v = ((const float4*)src)[threadIdx.x];
  unsigned int u0 = (unsigned)f2bf(v.x) | ((unsigned)f2bf(v.y) << 16);
  unsigned int u1 = (unsigned)f2bf(v.z) | ((unsigned)f2bf(v.w) << 16);
  ((u32x2*)(xw + (size_t)row * Cdim))[threadIdx.x] = (u32x2){u0, u1};
}

// ---------- GEMM: C[M=66560, N] = A[M,768] @ Bw[N,768]^T + bias ----------
// r10/r12 configuration (proven 317 us QKV): m97 mainloop, 128x128 tile,
// BK=64, 4 waves 2x2 (64x64 each), single 32 KB LDS buffer, 4 blocks/CU
// (launch_bounds 256,4), both-sides XOR-8 swizzle (0 conflicts), coalesced
// LDS-staged epilogue. MODE 0: qkv bf16 + fused RoPE. MODE 1: fp32
// window-merge + unseen mean. UNCHANGED vs r12 (attribution anchor).
template<int MODE, int NTILES>
__global__ __launch_bounds__(256, 4) void k_gemm(
    const unsigned short* __restrict__ A, const unsigned short* __restrict__ Bw,
    const float* __restrict__ bias, const float* __restrict__ rope,
    unsigned short* __restrict__ Cb, float* __restrict__ outp) {
  constexpr int K = 768;
  __shared__ alignas(16) unsigned short As[128 * 64];   // 16 KB
  __shared__ alignas(16) unsigned short Bs[128 * 64];   // 16 KB

  // bijective XCD swizzle
  constexpr int nwg = 520 * NTILES;
  constexpr int q8 = nwg / 8, r8 = nwg % 8;
  int id = blockIdx.x;
  int xcd = id & 7, lid = id >> 3;
  int wg = (xcd < r8 ? xcd * (q8 + 1) : r8 * (q8 + 1) + (xcd - r8) * q8) + lid;
  int mtile = wg / NTILES, ntile = wg - mtile * NTILES;
  int m0 = mtile * 128, n0 = ntile * 128;

  int tid = threadIdx.x;
  int lane = tid & 63, wid = tid >> 6;
  int lq = lane & 15, lg = lane >> 4;
  int wm = (wid >> 1) * 64;              // wave M offset (0 or 64)
  int wn = (wid & 1) * 64;               // wave N offset (0 or 64)

  f32x4 acc[4][4];
  #pragma unroll
  for (int i = 0; i < 4; ++i)
    #pragma unroll
    for (int j = 0; j < 4; ++j) acc[i][j] = (f32x4){0.f, 0.f, 0.f, 0.f};

  for (int kt = 0; kt < K / 64; ++kt) {
    int k0 = kt * 64;
    #pragma unroll
    for (int c = 0; c < 4; ++c) {
      int chunk = c * 256 + tid;
      int row = chunk >> 3, kc = chunk & 7;
      int skc = kc ^ (row & 7);
      gload_lds16(A + (size_t)(m0 + row) * K + k0 + skc * 8,
                  As + (size_t)(c * 256 + (tid & ~63)) * 8);
    }
    #pragma unroll
    for (int c = 0; c < 4; ++c) {
      int chunk = c * 256 + tid;
      int row = chunk >> 3, kc = chunk & 7;
      int skc = kc ^ (row & 7);
      gload_lds16(Bw + (size_t)(n0 + row) * K + k0 + skc * 8,
                  Bs + (size_t)(c * 256 + (tid & ~63)) * 8);
    }
    asm volatile("s_waitcnt vmcnt(0)" ::: "memory");
    __syncthreads();
    #pragma unroll
    for (int ks = 0; ks < 2; ++ks) {
      bf16x8 af[4], bfr[4];
      #pragma unroll
      for (int mt = 0; mt < 4; ++mt) {
        int row = wm + mt * 16 + lq;
        int ch = ((ks << 2) + lg) ^ (row & 7);
        af[mt] = *(const bf16x8*)(As + row * 64 + ch * 8);
      }
      #pragma unroll
      for (int nt = 0; nt < 4; ++nt) {
        int row = wn + nt * 16 + lq;
        int ch = ((ks << 2) + lg) ^ (row & 7);
        bfr[nt] = *(const bf16x8*)(Bs + row * 64 + ch * 8);
      }
      #pragma unroll
      for (int mt = 0; mt < 4; ++mt)
        #pragma unroll
        for (int nt = 0; nt < 4; ++nt)
          acc[mt][nt] = __builtin_amdgcn_mfma_f32_16x16x32_bf16(af[mt], bfr[nt], acc[mt][nt], 0, 0, 0);
    }
    __syncthreads();
  }

  // ---- coalesced LDS-staged epilogue (overlays As/Bs: 32 KB) ----
  if (MODE == 0) {
    unsigned short* ct = As;
    #pragma unroll
    for (int mt = 0; mt < 4; ++mt) {
      #pragma unroll
      for (int r = 0; r < 4; ++r) {
        int lrow = wm + mt * 16 + (lg << 2) + r;
        int grow = m0 + lrow;
        int w = grow / NT, t = grow - w * NT;
        int wy = (w >> 3) & 7, wx = w & 7;
        int py = (wy << 3) + (t >> 3), px = (wx << 3) + (t & 7);
        #pragma unroll
        for (int a = 0; a < 2; ++a) {
          int cn0 = wn + a * 32 + lq;          // tile-local col [0,128)
          int col0 = n0 + cn0, col1 = col0 + 16;
          float v0 = acc[mt][2 * a][r] + bias[col0];
          float v1 = acc[mt][2 * a + 1][r] + bias[col1];
          if (col0 < 1536 && t != 64) {        // RoPE on q/k image tokens
            int p = a ? px : py;               // (col0 & 63) >> 5 == a
            const float* rp = rope + ((p << 4) + lq) * 2;
            float cc = rp[0], ss = rp[1];
            float o0 = v0 * cc - v1 * ss;
            float o1 = v1 * cc + v0 * ss;
            v0 = o0; v1 = o1;
          }
          int b0 = (lrow * 256 + cn0 * 2) ^ ((lrow & 7) << 4);
          int b1 = (lrow * 256 + (cn0 + 16) * 2) ^ ((lrow & 7) << 4);
          *(unsigned short*)((char*)ct + b0) = f2bf(v0);
          *(unsigned short*)((char*)ct + b1) = f2bf(v1);
        }
      }
    }
    __syncthreads();
    #pragma unroll
    for (int j = 0; j < 8; ++j) {
      int idx = j * 256 + tid;
      int row = idx >> 4, c = idx & 15;        // 16 16B-chunks per 128-col row
      u32x4 v = *(const u32x4*)((char*)ct + row * 256 + ((c ^ (row & 7)) << 4));
      *(u32x4*)(Cb + (size_t)(m0 + row) * C3 + n0 + c * 8) = v;
    }
  } else {
    float* cf = (float*)As;
    #pragma unroll
    for (int half = 0; half < 2; ++half) {
      if ((wm >> 6) == half) {
        #pragma unroll
        for (int mt = 0; mt < 4; ++mt) {
          #pragma unroll
          for (int r = 0; r < 4; ++r) {
            int lrow = mt * 16 + (lg << 2) + r;  // 0..63
            int grow = m0 + half * 64 + lrow;
            int w = grow / NT, t = grow - w * NT;
            #pragma unroll
            for (int a = 0; a < 2; ++a) {
              int cn0 = wn + a * 32 + lq;
              int col0 = n0 + cn0, col1 = col0 + 16;
              float v0 = acc[mt][2 * a][r] + bias[col0];
              float v1 = acc[mt][2 * a + 1][r] + bias[col1];
              if (t == 64) {
                float* ub = outp + OUT_IMG + (size_t)(w >> 6) * Cdim;
                atomicAdd(ub + col0, v0 * (1.f / 64.f));
                atomicAdd(ub + col1, v1 * (1.f / 64.f));
              } else {
                int b0 = (lrow * 512 + cn0 * 4) ^ ((lrow & 7) << 4);
                int b1 = (lrow * 512 + (cn0 + 16) * 4) ^ ((lrow & 7) << 4);
                *(float*)((char*)cf + b0) = v0;
                *(float*)((char*)cf + b1) = v1;
              }
            }
          }
        }
      }
      __syncthreads();
      #pragma unroll
      for (int j = 0; j < 8; ++j) {
        int idx = j * 256 + tid;
        int row = idx >> 5, c = idx & 31;      // 32 16B-chunks per 128-col row
        int grow = m0 + half * 64 + row;
        int w = grow / NT, t = grow - w * NT;
        if (t != 64) {
          int wy = (w >> 3) & 7, wx = w & 7;
          int py = (wy << 3) + (t >> 3), px = (wx << 3) + (t & 7);
          u32x4 v = *(const u32x4*)((char*)cf + row * 512 + ((c ^ (row & 7)) << 4));
          *(u32x4*)(outp + ((size_t)(w >> 6) * 4096 + py * 64 + px) * Cdim + n0 + c * 4) = v;
        }
      }
      __syncthreads();
    }
  }
}

// ---------- K4: attention, 1 wave per (window, head) ----------
// CHANGE vs r12: k_vt ELIMINATED. V-tile staged in-block: coalesced 16B
// loads from qkv -> ds_write_b128 into padded [64][68] LDS -> transposed
// scalar ds_read_u16 fragment reads (single-wave block: waitcnt ordering
// only, no barriers). Unseen token (t=64) via rank-1 VALU update (r6
// pattern). P = 4 KB, no zero-init, PV uses ks=0..1 only.
__global__ __launch_bounds__(64) void k_attn(const unsigned short* __restrict__ qkv,
                                             unsigned short* __restrict__ att) {
  __shared__ alignas(16) unsigned short P[16 * PS];     // 4 KB
  __shared__ alignas(16) unsigned short Vs[64 * 68];    // 8.5 KB padded [t][68]
  int h = blockIdx.x, w = blockIdx.y;
  int lane = threadIdx.x;
  int lq = lane & 15, lg = lane >> 4;

  const unsigned short* qb = qkv + (size_t)w * NT * C3 + h * 64;
  const unsigned short* kb = qb + 768;
  const unsigned short* vsrc = qb + 1536;

  // stage V[64][64] -> padded LDS [64][68] (per-lane scatter writes)
  {
    int ts = lane >> 3, c = lane & 7;
    #pragma unroll
    for (int j = 0; j < 8; ++j) {
      int tt = j * 8 + ts;
      u32x4 v = *(const u32x4*)(vsrc + (size_t)tt * C3 + c * 8);
      *(u32x4*)(Vs + tt * 68 + c * 8) = v;
    }
  }

  bf16x8 kf[5][2];
  #pragma unroll
  for (int kt = 0; kt < 5; ++kt)
    #pragma unroll
    for (int ks = 0; ks < 2; ++ks)
      kf[kt][ks] = *(const bf16x8*)(kb + (size_t)(kt * 16 + lq) * C3 + ks * 32 + lg * 8);

  // unseen-token V row (t = 64); output row d = dt*16 + lg*4 + r
  const unsigned short* v64p = vsrc + (size_t)64 * C3;
  float v64f[4][4];
  #pragma unroll
  for (int dt = 0; dt < 4; ++dt) {
    u32x2 u = *(const u32x2*)(v64p + dt * 16 + lg * 4);
    v64f[dt][0] = bf2f((unsigned short)(u[0] & 0xffff));
    v64f[dt][1] = bf2f((unsigned short)(u[0] >> 16));
    v64f[dt][2] = bf2f((unsigned short)(u[1] & 0xffff));
    v64f[dt][3] = bf2f((unsigned short)(u[1] >> 16));
  }

  // transposed V fragments: vf[ks][dt] elem j = V[t = ks*32+lg*8+j][d = dt*16+lq]
  bf16x8 vf[2][4];
  #pragma unroll
  for (int ks = 0; ks < 2; ++ks)
    #pragma unroll
    for (int dt = 0; dt < 4; ++dt) {
      int d = dt * 16 + lq;
      int t0 = ks * 32 + lg * 8;
      bf16x8 v;
      #pragma unroll
      for (int j = 0; j < 8; ++j)
        v[j] = *(const __bf16*)(Vs + (t0 + j) * 68 + d);
      vf[ks][dt] = v;
    }

  #pragma unroll 1
  for (int qt = 0; qt < 5; ++qt) {
    bf16x8 qf[2];
    #pragma unroll
    for (int ks = 0; ks < 2; ++ks)
      qf[ks] = *(const bf16x8*)(qb + (size_t)(qt * 16 + lq) * C3 + ks * 32 + lg * 8);

    f32x4 sa[5];
    #pragma unroll
    for (int kt = 0; kt < 5; ++kt) {
      sa[kt] = (f32x4){0.f, 0.f, 0.f, 0.f};
      #pragma unroll
      for (int ks = 0; ks < 2; ++ks)
        sa[kt] = __builtin_amdgcn_mfma_f32_16x16x32_bf16(kf[kt][ks], qf[ks], sa[kt], 0, 0, 0);
    }
    float pv[5][4];
    float m = -1e30f;
    #pragma unroll
    for (int kt = 0; kt < 5; ++kt)
      #pragma unroll
      for (int r = 0; r < 4; ++r) {
        int tok = kt * 16 + lg * 4 + r;
        float s = sa[kt][r] * 0.125f;
        bool ok = tok < 65;
        pv[kt][r] = ok ? s : -1e30f;
        m = (ok && s > m) ? s : m;
      }
    m = fmaxf(m, __shfl_xor(m, 16));
    m = fmaxf(m, __shfl_xor(m, 32));
    float sum = 0.f;
    #pragma unroll
    for (int kt = 0; kt < 5; ++kt)
      #pragma unroll
      for (int r = 0; r < 4; ++r) {
        float e = (pv[kt][r] > -1e29f) ? exp2f((pv[kt][r] - m) * 1.44269504f) : 0.f;
        pv[kt][r] = e;
        sum += e;
      }
    sum += __shfl_xor(sum, 16);
    sum += __shfl_xor(sum, 32);
    float rinv = 1.f / sum;

    int q = qt * 16 + lq;
    #pragma unroll
    for (int kt = 0; kt < 4; ++kt) {     // image tokens 0..63 only
      unsigned int u0 = (unsigned)f2bf(pv[kt][0] * rinv) | ((unsigned)f2bf(pv[kt][1] * rinv) << 16);
      unsigned int u1 = (unsigned)f2bf(pv[kt][2] * rinv) | ((unsigned)f2bf(pv[kt][3] * rinv) << 16);
      int byteo = (lq * (PS * 2) + kt * 32 + lg * 8) ^ ((lq & 7) << 4);
      *(u32x2*)((char*)P + byteo) = (u32x2){u0, u1};
    }
    float p64 = pv[4][0] * rinv;         // token 64 prob (valid in lg==0 lanes)
    p64 = __shfl(p64, lq);               // broadcast for this lane's output column
    asm volatile("s_waitcnt lgkmcnt(0)" ::: "memory");

    bf16x8 bp[2];
    #pragma unroll
    for (int ks = 0; ks < 2; ++ks) {
      int byteo = (lq * (PS * 2) + ks * 64 + lg * 16) ^ ((lq & 7) << 4);
      bp[ks] = *(const bf16x8*)((char*)P + byteo);
    }
    #pragma unroll
    for (int dt = 0; dt < 4; ++dt) {
      f32x4 o = (f32x4){0.f, 0.f, 0.f, 0.f};
      #pragma unroll
      for (int ks = 0; ks < 2; ++ks)
        o = __builtin_amdgcn_mfma_f32_16x16x32_bf16(vf[ks][dt], bp[ks], o, 0, 0, 0);
      #pragma unroll
      for (int r = 0; r < 4; ++r) o[r] += p64 * v64f[dt][r];
      if (q < 65) {
        unsigned int u0 = (unsigned)f2bf(o[0]) | ((unsigned)f2bf(o[1]) << 16);
        unsigned int u1 = (unsigned)f2bf(o[2]) | ((unsigned)f2bf(o[3]) << 16);
        *(u32x2*)(att + (size_t)(w * NT + q) * Cdim + h * 64 + dt * 16 + lg * 4) = (u32x2){u0, u1};
      }
    }
  }
}

// ---------- host ----------
extern "C" void kernel_launch(void* const* d_in, const int* in_sizes, int n_in,
                              void* d_out, int out_size, void* d_ws, size_t ws_size,
                              hipStream_t stream) {
  const float* x_img  = (const float*)d_in[0];
  const float* unseen = (const float*)d_in[2];
  const float* qkv_w  = (const float*)d_in[3];
  const float* qkv_b  = (const float*)d_in[4];
  const float* proj_w = (const float*)d_in[5];
  const float* proj_b = (const float*)d_in[6];

  char* ws = (char*)d_ws;
  size_t off = 0;
  auto alloc = [&](size_t bytes) { void* p = ws + off; off = (off + bytes + 255) & ~(size_t)255; return p; };
  unsigned short* xw  = (unsigned short*)alloc((size_t)ROWS * Cdim * 2);       // reused as attn-out
  unsigned short* qkv = (unsigned short*)alloc((size_t)ROWS_PAD * C3 * 2);
  unsigned short* wqb = (unsigned short*)alloc((size_t)C3 * Cdim * 2);
  unsigned short* wpb = (unsigned short*)alloc((size_t)Cdim * Cdim * 2);
  float* rope = (float*)alloc(64 * 16 * 2 * sizeof(float));

  hipMemsetAsync((float*)d_out + OUT_IMG, 0, 16 * Cdim * sizeof(float), stream);

  k_prep<<<512, 256, 0, stream>>>(qkv_w, proj_w, wqb, wpb, rope);
  k_xw<<<ROWS, 192, 0, stream>>>(x_img, unseen, xw);
  k_gemm<0, 18><<<520 * 18, 256, 0, stream>>>(xw, wqb, qkv_b, rope, qkv, nullptr);
  k_attn<<<dim3(12, 1024), 64, 0, stream>>>(qkv, xw);
  k_gemm<1, 6><<<520 * 6, 256, 0, stream>>>(xw, wpb, proj_b, nullptr, nullptr, (float*)d_out);
}